// Round 3
// baseline (188.027 us; speedup 1.0000x reference)
//
#include <hip/hip_runtime.h>

#define S   512
#define OUT 512
#define NB  8
#define CB  32

// ---------------------------------------------------------------------------
// Kernel 1 (v3): wave-per-row inverse-CDF coords, register-resident.
// 16 blocks x 64 threads; block = (axis, n). Each lane owns 8 cells.
// All reductions via shuffles; LDS only holds the final cumsum for the
// per-output binary search. Output packed: int2 {i0, bits(w)}.
// ---------------------------------------------------------------------------
__global__ __launch_bounds__(64) void coords_kernel(
    const float* __restrict__ attx, const float* __restrict__ atty,
    int2* __restrict__ coords)               // [2][8][512]
{
  __shared__ double sc[S];
  const int lane = threadIdx.x;              // 0..63
  const int n    = blockIdx.x & 7;
  const int axis = blockIdx.x >> 3;
  const float* att = (axis == 0 ? attx : atty) + n * S;

  double a[8];
#pragma unroll
  for (int k = 0; k < 8; ++k) a[k] = (double)att[lane * 8 + k];

  // total sum (butterfly all-reduce)
  double tot = 0.0;
#pragma unroll
  for (int k = 0; k < 8; ++k) tot += a[k];
#pragma unroll
  for (int off = 32; off > 0; off >>= 1) tot += __shfl_xor(tot, off);

#pragma unroll
  for (int k = 0; k < 8; ++k) a[k] = a[k] / tot * (double)OUT;
  const double thr = (double)(4 * OUT) / (double)S;   // = 4.0

  // 5 clip + redistribute iterations, fully in registers
  for (int it = 0; it < 5; ++it) {
    double s = 0.0;
#pragma unroll
    for (int k = 0; k < 8; ++k) { a[k] = a[k] < thr ? a[k] : thr; s += a[k]; }
#pragma unroll
    for (int off = 32; off > 0; off >>= 1) s += __shfl_xor(s, off);
    const double corr = ((double)OUT - s) / (double)S;
#pragma unroll
    for (int k = 0; k < 8; ++k) a[k] += corr;
  }

  // inclusive prefix within lane
  double p[8]; double run = 0.0;
#pragma unroll
  for (int k = 0; k < 8; ++k) { run += a[k]; p[k] = run; }
  // exclusive wave scan of per-lane totals
  double v = run;
#pragma unroll
  for (int off = 1; off < 64; off <<= 1) {
    double t = __shfl_up(v, off);
    if (lane >= off) v += t;
  }
  const double excl = v - run;
#pragma unroll
  for (int k = 0; k < 8; ++k) sc[lane * 8 + k] = excl + p[k];
  __syncthreads();

  const double step = sc[S - 1] / (double)OUT;

#pragma unroll
  for (int k = 0; k < 8; ++k) {
    const int ox = lane * 8 + k;
    const double tgt = step * (double)(ox + 1);

    int lo = 0, hi = S;
    while (lo < hi) {
      int mid = (lo + hi) >> 1;
      if (sc[mid] < tgt) lo = mid + 1; else hi = mid;
    }
    int j = lo < S - 1 ? lo : S - 1;

    double right = sc[j];
    double left  = (j > 0) ? sc[j - 1] : 0.0;
    double denom = right - left;
    if (denom < 1e-8) denom = 1e-8;
    double frac = (tgt - left) / denom;
    frac = frac < 0.0 ? 0.0 : (frac > 1.0 ? 1.0 : frac);

    double pp  = ((double)j + frac) / (double)S * (double)(S - 1);
    double p0f = floor(pp);
    double w   = pp - p0f;
    int i0 = (int)p0f;
    i0 = i0 < 0 ? 0 : (i0 > S - 1 ? S - 1 : i0);

    coords[(axis * NB + n) * S + ox] = make_int2(i0, __float_as_int((float)w));
  }
}

// ---------------------------------------------------------------------------
// Kernel 2 (v3): one block per (n, c, pair of output rows). 512 threads.
// Stage the (up to) 4 needed input rows into LDS with coalesced float4
// loads, gather along x from LDS, write two contiguous output rows.
// XCD swizzle keeps each batch's blocks on one XCD for L2 row reuse.
// ---------------------------------------------------------------------------
__global__ __launch_bounds__(512) void sample_kernel(
    const float* __restrict__ data, const int2* __restrict__ coords,
    float* __restrict__ out)
{
  __shared__ float rows[4][S];               // A0, B0, A1, B1

  // 65536 blocks; 65536 % 8 == 0 -> bijective XCD swizzle.
  int b = (int)blockIdx.x;
  b = (b & 7) * (NB * CB * (OUT / 2) / 8) + (b >> 3);
  const int oyp = b & 255;                   // row-pair index
  const int c   = (b >> 8) & (CB - 1);
  const int n   = b >> 13;

  const int tid = threadIdx.x;
  const float* plane = data + (size_t)(n * CB + c) * S * S;

  // stage: thread t loads float4 (t&127) of staged row (t>>7)
  {
    const int rr = tid >> 7;                 // 0..3 -> (row-in-pair rr>>1, A/B rr&1)
    const int f4 = tid & 127;
    const int2 cy = coords[(NB + n) * S + oyp * 2 + (rr >> 1)];
    int ri = cy.x + (rr & 1);
    ri = ri < S - 1 ? ri : S - 1;
    ((float4*)rows[rr])[f4] = ((const float4*)(plane + (size_t)ri * S))[f4];
  }

  const int r  = tid >> 8;                   // my output row within pair
  const int oy = oyp * 2 + r;
  const int2 cy = coords[(NB + n) * S + oy];
  const float wy = __int_as_float(cy.y);

  __syncthreads();

  const float* rA = rows[2 * r];
  const float* rB = rows[2 * r + 1];

  const int oxb = (tid & 255) * 2;
  float vv[2];
#pragma unroll
  for (int k = 0; k < 2; ++k) {
    const int ox = oxb + k;
    const int2 cx = coords[n * S + ox];
    const int   i0x = cx.x;
    const float wx  = __int_as_float(cx.y);
    const int   i1x = (i0x + 1 < S) ? i0x + 1 : S - 1;
    const float a  = rA[i0x];
    const float bb = rA[i1x];
    const float p  = rB[i0x];
    const float q  = rB[i1x];
    const float top = a + wx * (bb - a);
    const float bot = p + wx * (q - p);
    vv[k] = top + wy * (bot - top);
  }

  float2* o = (float2*)(out + ((size_t)(n * CB + c) * S + oy) * (size_t)OUT + oxb);
  *o = make_float2(vv[0], vv[1]);
}

extern "C" void kernel_launch(void* const* d_in, const int* in_sizes, int n_in,
                              void* d_out, int out_size, void* d_ws, size_t ws_size,
                              hipStream_t stream) {
  const float* data = (const float*)d_in[0];
  const float* attx = (const float*)d_in[1];
  const float* atty = (const float*)d_in[2];
  float* out = (float*)d_out;

  // Workspace: int2 coords[2][8][512]  (x coords then y coords), 64 KB
  int2* coords = (int2*)d_ws;

  coords_kernel<<<16, 64, 0, stream>>>(attx, atty, coords);

  const int nblocks = NB * CB * (OUT / 2);   // 65536
  sample_kernel<<<nblocks, 512, 0, stream>>>(data, coords, out);
}

// Round 4
// 149.181 us; speedup vs baseline: 1.2604x; 1.2604x over previous
//
#include <hip/hip_runtime.h>

#define S   512
#define OUT 512
#define NB  8
#define CB  32

// ---------------------------------------------------------------------------
// Kernel 1 (v3): wave-per-row inverse-CDF coords, register-resident.
// 16 blocks x 64 threads; block = (axis, n). Each lane owns 8 cells.
// All reductions via shuffles; LDS only holds the final cumsum for the
// per-output binary search. Output packed: int2 {i0, bits(w)}.
// ---------------------------------------------------------------------------
__global__ __launch_bounds__(64) void coords_kernel(
    const float* __restrict__ attx, const float* __restrict__ atty,
    int2* __restrict__ coords)               // [2][8][512]
{
  __shared__ double sc[S];
  const int lane = threadIdx.x;              // 0..63
  const int n    = blockIdx.x & 7;
  const int axis = blockIdx.x >> 3;
  const float* att = (axis == 0 ? attx : atty) + n * S;

  double a[8];
#pragma unroll
  for (int k = 0; k < 8; ++k) a[k] = (double)att[lane * 8 + k];

  // total sum (butterfly all-reduce)
  double tot = 0.0;
#pragma unroll
  for (int k = 0; k < 8; ++k) tot += a[k];
#pragma unroll
  for (int off = 32; off > 0; off >>= 1) tot += __shfl_xor(tot, off);

#pragma unroll
  for (int k = 0; k < 8; ++k) a[k] = a[k] / tot * (double)OUT;
  const double thr = (double)(4 * OUT) / (double)S;   // = 4.0

  // 5 clip + redistribute iterations, fully in registers
  for (int it = 0; it < 5; ++it) {
    double s = 0.0;
#pragma unroll
    for (int k = 0; k < 8; ++k) { a[k] = a[k] < thr ? a[k] : thr; s += a[k]; }
#pragma unroll
    for (int off = 32; off > 0; off >>= 1) s += __shfl_xor(s, off);
    const double corr = ((double)OUT - s) / (double)S;
#pragma unroll
    for (int k = 0; k < 8; ++k) a[k] += corr;
  }

  // inclusive prefix within lane
  double p[8]; double run = 0.0;
#pragma unroll
  for (int k = 0; k < 8; ++k) { run += a[k]; p[k] = run; }
  // exclusive wave scan of per-lane totals
  double v = run;
#pragma unroll
  for (int off = 1; off < 64; off <<= 1) {
    double t = __shfl_up(v, off);
    if (lane >= off) v += t;
  }
  const double excl = v - run;
#pragma unroll
  for (int k = 0; k < 8; ++k) sc[lane * 8 + k] = excl + p[k];
  __syncthreads();

  const double step = sc[S - 1] / (double)OUT;

#pragma unroll
  for (int k = 0; k < 8; ++k) {
    const int ox = lane * 8 + k;
    const double tgt = step * (double)(ox + 1);

    int lo = 0, hi = S;
    while (lo < hi) {
      int mid = (lo + hi) >> 1;
      if (sc[mid] < tgt) lo = mid + 1; else hi = mid;
    }
    int j = lo < S - 1 ? lo : S - 1;

    double right = sc[j];
    double left  = (j > 0) ? sc[j - 1] : 0.0;
    double denom = right - left;
    if (denom < 1e-8) denom = 1e-8;
    double frac = (tgt - left) / denom;
    frac = frac < 0.0 ? 0.0 : (frac > 1.0 ? 1.0 : frac);

    double pp  = ((double)j + frac) / (double)S * (double)(S - 1);
    double p0f = floor(pp);
    double w   = pp - p0f;
    int i0 = (int)p0f;
    i0 = i0 < 0 ? 0 : (i0 > S - 1 ? S - 1 : i0);

    coords[(axis * NB + n) * S + ox] = make_int2(i0, __float_as_int((float)w));
  }
}

// ---------------------------------------------------------------------------
// Kernel 2 (v4 = proven v2 geometry): one block per (n, c, output row),
// 256 threads, 4 KB LDS. Stage the two needed input rows with coalesced
// float4 loads, gather along x from LDS, write one contiguous output row.
// Coord loads packed: one int4 per thread (both x-pairs), int2 broadcast
// for y. Bijective XCD swizzle keeps each batch's blocks on one XCD.
// ---------------------------------------------------------------------------
__global__ __launch_bounds__(256) void sample_kernel(
    const float* __restrict__ data, const int2* __restrict__ coords,
    float* __restrict__ out)
{
  __shared__ float rA[S];
  __shared__ float rB[S];

  // 131072 blocks; 131072 % 8 == 0 -> bijective XCD swizzle.
  int b = (int)blockIdx.x;
  b = (b & 7) * (NB * CB * OUT / 8) + (b >> 3);
  const int oy = b & (OUT - 1);
  const int c  = (b >> 9) & (CB - 1);
  const int n  = b >> 14;

  const int tid = threadIdx.x;

  const int2 cy = coords[(NB + n) * S + oy];       // broadcast 8B load
  const int   i0y = cy.x;
  const float wy  = __int_as_float(cy.y);
  const int   i1y = (i0y + 1 < S) ? i0y + 1 : S - 1;

  const float4* rowA = (const float4*)(data + (((size_t)(n * CB + c) * S) + i0y) * (size_t)S);
  const float4* rowB = (const float4*)(data + (((size_t)(n * CB + c) * S) + i1y) * (size_t)S);

  // stage: 128 float4 per row; threads 0-127 -> rowA, 128-255 -> rowB
  if (tid < 128) ((float4*)rA)[tid]       = rowA[tid];
  else           ((float4*)rB)[tid - 128] = rowB[tid - 128];

  // both x coord pairs for this thread in one 16B load:
  // {i0x(2t), w(2t), i0x(2t+1), w(2t+1)}
  const int4 cc = ((const int4*)(coords + n * S))[tid];

  __syncthreads();

  float vv[2];
#pragma unroll
  for (int k = 0; k < 2; ++k) {
    const int   i0x = k == 0 ? cc.x : cc.z;
    const float wx  = __int_as_float(k == 0 ? cc.y : cc.w);
    const int   i1x = (i0x + 1 < S) ? i0x + 1 : S - 1;
    const float a  = rA[i0x];
    const float bb = rA[i1x];
    const float p  = rB[i0x];
    const float q  = rB[i1x];
    const float top = a + wx * (bb - a);
    const float bot = p + wx * (q - p);
    vv[k] = top + wy * (bot - top);
  }

  float2* o = (float2*)(out + (((size_t)(n * CB + c) * S) + oy) * (size_t)OUT + tid * 2);
  *o = make_float2(vv[0], vv[1]);
}

extern "C" void kernel_launch(void* const* d_in, const int* in_sizes, int n_in,
                              void* d_out, int out_size, void* d_ws, size_t ws_size,
                              hipStream_t stream) {
  const float* data = (const float*)d_in[0];
  const float* attx = (const float*)d_in[1];
  const float* atty = (const float*)d_in[2];
  float* out = (float*)d_out;

  // Workspace: int2 coords[2][8][512]  (x coords then y coords), 64 KB
  int2* coords = (int2*)d_ws;

  coords_kernel<<<16, 64, 0, stream>>>(attx, atty, coords);

  const int nblocks = NB * CB * OUT;   // 131072
  sample_kernel<<<nblocks, 256, 0, stream>>>(data, coords, out);
}

// Round 5
// 127.615 us; speedup vs baseline: 1.4734x; 1.1690x over previous
//
#include <hip/hip_runtime.h>

#define S    512
#define OUT  512
#define NB   8
#define CB   32
#define TRW  16                      // rows per wave
#define NBLK (NB * CB * 8)           // 256 planes * 8 blocks/plane = 2048

// ---------------------------------------------------------------------------
// Kernel 1 (v3, unchanged): wave-per-row inverse-CDF coords, register-resident.
// ---------------------------------------------------------------------------
__global__ __launch_bounds__(64) void coords_kernel(
    const float* __restrict__ attx, const float* __restrict__ atty,
    int2* __restrict__ coords)               // [2][8][512]
{
  __shared__ double sc[S];
  const int lane = threadIdx.x;              // 0..63
  const int n    = blockIdx.x & 7;
  const int axis = blockIdx.x >> 3;
  const float* att = (axis == 0 ? attx : atty) + n * S;

  double a[8];
#pragma unroll
  for (int k = 0; k < 8; ++k) a[k] = (double)att[lane * 8 + k];

  double tot = 0.0;
#pragma unroll
  for (int k = 0; k < 8; ++k) tot += a[k];
#pragma unroll
  for (int off = 32; off > 0; off >>= 1) tot += __shfl_xor(tot, off);

#pragma unroll
  for (int k = 0; k < 8; ++k) a[k] = a[k] / tot * (double)OUT;
  const double thr = (double)(4 * OUT) / (double)S;   // = 4.0

  for (int it = 0; it < 5; ++it) {
    double s = 0.0;
#pragma unroll
    for (int k = 0; k < 8; ++k) { a[k] = a[k] < thr ? a[k] : thr; s += a[k]; }
#pragma unroll
    for (int off = 32; off > 0; off >>= 1) s += __shfl_xor(s, off);
    const double corr = ((double)OUT - s) / (double)S;
#pragma unroll
    for (int k = 0; k < 8; ++k) a[k] += corr;
  }

  double p[8]; double run = 0.0;
#pragma unroll
  for (int k = 0; k < 8; ++k) { run += a[k]; p[k] = run; }
  double v = run;
#pragma unroll
  for (int off = 1; off < 64; off <<= 1) {
    double t = __shfl_up(v, off);
    if (lane >= off) v += t;
  }
  const double excl = v - run;
#pragma unroll
  for (int k = 0; k < 8; ++k) sc[lane * 8 + k] = excl + p[k];
  __syncthreads();

  const double step = sc[S - 1] / (double)OUT;

#pragma unroll
  for (int k = 0; k < 8; ++k) {
    const int ox = lane * 8 + k;
    const double tgt = step * (double)(ox + 1);

    int lo = 0, hi = S;
    while (lo < hi) {
      int mid = (lo + hi) >> 1;
      if (sc[mid] < tgt) lo = mid + 1; else hi = mid;
    }
    int j = lo < S - 1 ? lo : S - 1;

    double right = sc[j];
    double left  = (j > 0) ? sc[j - 1] : 0.0;
    double denom = right - left;
    if (denom < 1e-8) denom = 1e-8;
    double frac = (tgt - left) / denom;
    frac = frac < 0.0 ? 0.0 : (frac > 1.0 ? 1.0 : frac);

    double pp  = ((double)j + frac) / (double)S * (double)(S - 1);
    double p0f = floor(pp);
    double w   = pp - p0f;
    int i0 = (int)p0f;
    i0 = i0 < 0 ? 0 : (i0 > S - 1 ? S - 1 : i0);

    coords[(axis * NB + n) * S + ox] = make_int2(i0, __float_as_int((float)w));
  }
}

// ---------------------------------------------------------------------------
// Kernel 2 (v5): barrier-free, wave-private pipelined staging.
// 2048 blocks x 256 threads (= 8192 waves = full chip at 100% occupancy).
// Each wave owns a 16-row output stripe of one (n,c) plane and a private
// 4 KB LDS buffer (rows A,B). Per row: issue next row's global float4 loads
// into registers, ds_write current row's registers to LDS, gather along x
// from LDS, compute, store. No __syncthreads anywhere; within-wave DS
// ordering guarantees correctness. Strided gather (ox = lane + 64k) keeps
// regular-region LDS reads at 2 lanes/bank (conflict-free).
// ---------------------------------------------------------------------------
__global__ __launch_bounds__(256) void sample_kernel(
    const float* __restrict__ data, const int2* __restrict__ coords,
    float* __restrict__ out)
{
  __shared__ float lds[4][2][S];             // 16 KB: per-wave rows A,B

  int b = (int)blockIdx.x;
  b = (b & 7) * (NBLK / 8) + (b >> 3);       // bijective XCD swizzle
  const int plane = b >> 3;                  // = n*CB + c, 0..255
  const int bip   = b & 7;                   // block-in-plane
  const int n     = plane >> 5;

  const int tid  = threadIdx.x;
  const int wv   = tid >> 6;
  const int lane = tid & 63;
  const int oy0  = bip * 64 + wv * TRW;

  const float* __restrict__ pl = data + (size_t)plane * (S * S);
  float* __restrict__       po = out  + (size_t)plane * (S * S);

  // hoisted x coords: this lane handles ox = lane + 64k, k = 0..7
  int   i0x[8], i1x[8];
  float wx[8];
#pragma unroll
  for (int k = 0; k < 8; ++k) {
    const int2 cx = coords[n * S + lane + 64 * k];
    i0x[k] = cx.x;
    i1x[k] = cx.x + 1 < S ? cx.x + 1 : S - 1;
    wx[k]  = __int_as_float(cx.y);
  }

  float* lA = lds[wv][0];
  float* lB = lds[wv][1];
  const int2* cyp = coords + (NB + n) * S + oy0;

  // prologue: issue loads for row 0
  int2 cy = cyp[0];
  int iA = cy.x;
  int iB = iA + 1 < S ? iA + 1 : S - 1;
  float4 ra0 = ((const float4*)(pl + (size_t)iA * S))[lane];
  float4 ra1 = ((const float4*)(pl + (size_t)iA * S))[lane + 64];
  float4 rb0 = ((const float4*)(pl + (size_t)iB * S))[lane];
  float4 rb1 = ((const float4*)(pl + (size_t)iB * S))[lane + 64];
  float wy = __int_as_float(cy.y);

  for (int r = 0; r < TRW; ++r) {
    // commit current row pair to wave-private LDS (this is where vmcnt waits)
    ((float4*)lA)[lane]      = ra0;
    ((float4*)lA)[lane + 64] = ra1;
    ((float4*)lB)[lane]      = rb0;
    ((float4*)lB)[lane + 64] = rb1;

    const float wyc = wy;

    // issue next row's loads (latency hides under this row's gather+compute)
    if (r + 1 < TRW) {
      cy = cyp[r + 1];
      iA = cy.x;
      iB = iA + 1 < S ? iA + 1 : S - 1;
      ra0 = ((const float4*)(pl + (size_t)iA * S))[lane];
      ra1 = ((const float4*)(pl + (size_t)iA * S))[lane + 64];
      rb0 = ((const float4*)(pl + (size_t)iB * S))[lane];
      rb1 = ((const float4*)(pl + (size_t)iB * S))[lane + 64];
      wy = __int_as_float(cy.y);
    }

    // gather along x from LDS, bilinear combine, coalesced scalar stores
    float* orow = po + (size_t)(oy0 + r) * OUT;
#pragma unroll
    for (int k = 0; k < 8; ++k) {
      const float a  = lA[i0x[k]];
      const float bb = lA[i1x[k]];
      const float p  = lB[i0x[k]];
      const float q  = lB[i1x[k]];
      const float top = a + wx[k] * (bb - a);
      const float bot = p + wx[k] * (q - p);
      orow[lane + 64 * k] = top + wyc * (bot - top);
    }
  }
}

extern "C" void kernel_launch(void* const* d_in, const int* in_sizes, int n_in,
                              void* d_out, int out_size, void* d_ws, size_t ws_size,
                              hipStream_t stream) {
  const float* data = (const float*)d_in[0];
  const float* attx = (const float*)d_in[1];
  const float* atty = (const float*)d_in[2];
  float* out = (float*)d_out;

  // Workspace: int2 coords[2][8][512]  (x coords then y coords), 64 KB
  int2* coords = (int2*)d_ws;

  coords_kernel<<<16, 64, 0, stream>>>(attx, atty, coords);

  sample_kernel<<<NBLK, 256, 0, stream>>>(data, coords, out);
}

// Round 6
// 127.261 us; speedup vs baseline: 1.4775x; 1.0028x over previous
//
#include <hip/hip_runtime.h>

#define S    512
#define OUT  512
#define NB   8
#define CB   32
#define TRW  16                      // rows per wave
#define NBLK (NB * CB * 8)           // 256 planes * 8 blocks/plane = 2048

// ---------------------------------------------------------------------------
// Kernel 1 (v3, unchanged): wave-per-row inverse-CDF coords, register-resident.
// ---------------------------------------------------------------------------
__global__ __launch_bounds__(64) void coords_kernel(
    const float* __restrict__ attx, const float* __restrict__ atty,
    int2* __restrict__ coords)               // [2][8][512]
{
  __shared__ double sc[S];
  const int lane = threadIdx.x;              // 0..63
  const int n    = blockIdx.x & 7;
  const int axis = blockIdx.x >> 3;
  const float* att = (axis == 0 ? attx : atty) + n * S;

  double a[8];
#pragma unroll
  for (int k = 0; k < 8; ++k) a[k] = (double)att[lane * 8 + k];

  double tot = 0.0;
#pragma unroll
  for (int k = 0; k < 8; ++k) tot += a[k];
#pragma unroll
  for (int off = 32; off > 0; off >>= 1) tot += __shfl_xor(tot, off);

#pragma unroll
  for (int k = 0; k < 8; ++k) a[k] = a[k] / tot * (double)OUT;
  const double thr = (double)(4 * OUT) / (double)S;   // = 4.0

  for (int it = 0; it < 5; ++it) {
    double s = 0.0;
#pragma unroll
    for (int k = 0; k < 8; ++k) { a[k] = a[k] < thr ? a[k] : thr; s += a[k]; }
#pragma unroll
    for (int off = 32; off > 0; off >>= 1) s += __shfl_xor(s, off);
    const double corr = ((double)OUT - s) / (double)S;
#pragma unroll
    for (int k = 0; k < 8; ++k) a[k] += corr;
  }

  double p[8]; double run = 0.0;
#pragma unroll
  for (int k = 0; k < 8; ++k) { run += a[k]; p[k] = run; }
  double v = run;
#pragma unroll
  for (int off = 1; off < 64; off <<= 1) {
    double t = __shfl_up(v, off);
    if (lane >= off) v += t;
  }
  const double excl = v - run;
#pragma unroll
  for (int k = 0; k < 8; ++k) sc[lane * 8 + k] = excl + p[k];
  __syncthreads();

  const double step = sc[S - 1] / (double)OUT;

#pragma unroll
  for (int k = 0; k < 8; ++k) {
    const int ox = lane * 8 + k;
    const double tgt = step * (double)(ox + 1);

    int lo = 0, hi = S;
    while (lo < hi) {
      int mid = (lo + hi) >> 1;
      if (sc[mid] < tgt) lo = mid + 1; else hi = mid;
    }
    int j = lo < S - 1 ? lo : S - 1;

    double right = sc[j];
    double left  = (j > 0) ? sc[j - 1] : 0.0;
    double denom = right - left;
    if (denom < 1e-8) denom = 1e-8;
    double frac = (tgt - left) / denom;
    frac = frac < 0.0 ? 0.0 : (frac > 1.0 ? 1.0 : frac);

    double pp  = ((double)j + frac) / (double)S * (double)(S - 1);
    double p0f = floor(pp);
    double w   = pp - p0f;
    int i0 = (int)p0f;
    i0 = i0 < 0 ? 0 : (i0 > S - 1 ? S - 1 : i0);

    coords[(axis * NB + n) * S + ox] = make_int2(i0, __float_as_int((float)w));
  }
}

// ---------------------------------------------------------------------------
// Kernel 2 (v6): barrier-free wave-private staging, upgraded:
//  - interleaved {A[i],B[i]} LDS pairs + pad -> one ds_read2_b64 per pixel
//  - prefetch depth 2 (two register slots, fully unrolled row loop)
//  - row-repeat skip: dense regions reuse the staged row pair (uniform branch)
// 2048 blocks x 256 threads; each wave owns 16 output rows of one plane.
// ---------------------------------------------------------------------------
__global__ __launch_bounds__(256) void sample_kernel(
    const float* __restrict__ data, const int2* __restrict__ coords,
    float* __restrict__ out)
{
  __shared__ float2 lds[4][S + 4];           // interleaved {A,B}, pad at [S]

  int b = (int)blockIdx.x;
  b = (b & 7) * (NBLK / 8) + (b >> 3);       // bijective XCD swizzle
  const int plane = b >> 3;                  // n*CB + c
  const int bip   = b & 7;
  const int n     = plane >> 5;

  const int tid  = threadIdx.x;
  const int wv   = tid >> 6;
  const int lane = tid & 63;
  const int oy0  = bip * 64 + wv * TRW;

  const float* __restrict__ pl = data + (size_t)plane * (S * S);
  float* __restrict__       po = out  + (size_t)plane * (S * S);

  // hoisted x coords: lane handles ox = lane + 64k
  int   ix[8];
  float wx[8];
#pragma unroll
  for (int k = 0; k < 8; ++k) {
    const int2 cx = coords[n * S + lane + 64 * k];
    ix[k] = cx.x;
    wx[k] = __int_as_float(cx.y);
  }

  float2* __restrict__ ab = lds[wv];
  const int2* __restrict__ cyp = coords + (NB + n) * S + oy0;

  float4 qa0[2], qa1[2], qb0[2], qb1[2];     // two prefetch slots

  // prologue: issue rows 0 and 1
  int2 c0 = cyp[0];
  const int a0 = c0.x;
  const int b0 = a0 + 1 < S ? a0 + 1 : S - 1;
  float wyA = __int_as_float(c0.y);
  {
    const float4* RA = (const float4*)(pl + (size_t)a0 * S);
    const float4* RB = (const float4*)(pl + (size_t)b0 * S);
    qa0[0] = RA[lane]; qa1[0] = RA[lane + 64];
    qb0[0] = RB[lane]; qb1[0] = RB[lane + 64];
  }
  int2 c1 = cyp[1];
  const int a1 = c1.x;
  float wyB = __int_as_float(c1.y);
  bool needN = (a1 != a0);
  if (needN) {
    const int b1 = a1 + 1 < S ? a1 + 1 : S - 1;
    const float4* RA = (const float4*)(pl + (size_t)a1 * S);
    const float4* RB = (const float4*)(pl + (size_t)b1 * S);
    qa0[1] = RA[lane]; qa1[1] = RA[lane + 64];
    qb0[1] = RB[lane]; qb1[1] = RB[lane + 64];
  }
  bool needC = true;
  int  prevA = a1;
  float wyC = 0.0f;

#pragma unroll
  for (int r = 0; r < TRW; ++r) {
    const int s = r & 1;

    // commit row r's pair to LDS (skipped when identical to previous row)
    if (needC) {
#pragma unroll
      for (int m = 0; m < 4; ++m) {
        ab[4 * lane + m] =
            make_float2(((const float*)&qa0[s])[m], ((const float*)&qb0[s])[m]);
        ab[4 * (lane + 64) + m] =
            make_float2(((const float*)&qa1[s])[m], ((const float*)&qb1[s])[m]);
      }
      if (lane == 63) ab[S] = make_float2(qa1[s].w, qb1[s].w);  // pad: clamp
    }

    // prefetch row r+2 into slot s (uniform skip if same input row pair)
    bool needNN = false;
    if (r + 2 < TRW) {
      int2 c2 = cyp[r + 2];
      const int a2 = c2.x;
      wyC = __int_as_float(c2.y);
      needNN = (a2 != prevA);
      if (needNN) {
        const int b2 = a2 + 1 < S ? a2 + 1 : S - 1;
        const float4* RA = (const float4*)(pl + (size_t)a2 * S);
        const float4* RB = (const float4*)(pl + (size_t)b2 * S);
        qa0[s] = RA[lane]; qa1[s] = RA[lane + 64];
        qb0[s] = RB[lane]; qb1[s] = RB[lane + 64];
      }
      prevA = a2;
    }

    // gather: one ds_read2_b64-pair per pixel, bilinear combine, store
    float* orow = po + (size_t)(oy0 + r) * OUT;
    const float wy = wyA;
#pragma unroll
    for (int k = 0; k < 8; ++k) {
      const float2 p0 = ab[ix[k]];
      const float2 p1 = ab[ix[k] + 1];       // pad makes this always valid
      const float top = p0.x + wx[k] * (p1.x - p0.x);
      const float bot = p0.y + wx[k] * (p1.y - p0.y);
      orow[lane + 64 * k] = top + wy * (bot - top);
    }

    wyA = wyB; wyB = wyC;
    needC = needN; needN = needNN;
  }
}

extern "C" void kernel_launch(void* const* d_in, const int* in_sizes, int n_in,
                              void* d_out, int out_size, void* d_ws, size_t ws_size,
                              hipStream_t stream) {
  const float* data = (const float*)d_in[0];
  const float* attx = (const float*)d_in[1];
  const float* atty = (const float*)d_in[2];
  float* out = (float*)d_out;

  // Workspace: int2 coords[2][8][512]  (x coords then y coords), 64 KB
  int2* coords = (int2*)d_ws;

  coords_kernel<<<16, 64, 0, stream>>>(attx, atty, coords);

  sample_kernel<<<NBLK, 256, 0, stream>>>(data, coords, out);
}